// Round 8
// baseline (314.677 us; speedup 1.0000x reference)
//
#include <hip/hip_runtime.h>
#include <stdint.h>

#pragma clang fp contract(off)

#define NN    300000
#define TOPK  6000u
#define KW    94
#define KPAD  6016
#define SORTN 8192
#define NCHUNK 16
#define CSZ   512
#define OUTK  300
#define ECAP  8192
#define ELDS  3072
#define NREP  8

// ---------------- workspace layout (bytes) ----------------
static constexpr size_t OFF_ROI    = 0;                                   // NN*16
static constexpr size_t OFF_KEY    = OFF_ROI + (size_t)NN * 16;           // NN*4
static constexpr size_t OFF_HIST16 = ((OFF_KEY + (size_t)NN * 4 + 255) & ~(size_t)255); // NREP*65536*4
static constexpr size_t OFF_HIST8  = OFF_HIST16 + (size_t)NREP * 65536 * 4; // 256*4
static constexpr size_t OFF_SCAL   = OFF_HIST8 + 256 * 4;                 // 256 B scalars
static constexpr size_t OFF_ECNT   = OFF_SCAL + 256;                      // 94*4, pad 512
static constexpr size_t ZERO_BYTES = (OFF_ECNT + 512) - OFF_HIST16;
static constexpr size_t OFF_HISTS  = OFF_ECNT + 512;                      // 65536*4 (summed, no zeroing)
static constexpr size_t OFF_SORT   = OFF_HISTS + 65536 * 4;               // SORTN*8
static constexpr size_t OFF_SELBOX = OFF_SORT + (size_t)SORTN * 8;        // KPAD*16
static constexpr size_t OFF_DIAG   = ((OFF_SELBOX + (size_t)KPAD * 16 + 255) & ~(size_t)255); // KPAD*8
static constexpr size_t OFF_ELIST  = OFF_DIAG + (size_t)KPAD * 8;         // KW*ECAP*4 ~= 3.0 MB

// scal[] layout: [0]=P16 bin, [1]=count_below16, [2]=T24 prefix, [3]=compact counter,
//                [4]=total valid count

__device__ __forceinline__ uint32_t score_key(float s) {
  uint32_t u = __float_as_uint(s);
  u = (u >> 31) ? ~u : (u | 0x80000000u);  // monotonic: ascending uint == ascending float
  return ~u;                               // invert: ascending uint == DESCENDING float
}

// bit-reversed histogram slot: consecutive bins -> distinct cache lines.
__device__ __forceinline__ uint32_t hslot(uint32_t b) { return __brev(b) >> 16; }

// ---------------- 1. decode + key + replicated 16-bit histogram ----------------
__global__ void k_decode(const float* __restrict__ cls, const float* __restrict__ reg,
                         const float* __restrict__ anchor, float4* __restrict__ roi,
                         uint32_t* __restrict__ key, uint32_t* __restrict__ hist16) {
  int i = blockIdx.x * blockDim.x + threadIdx.x;
  if (i >= NN) return;
  // softmax(cls)[1], bit-identical op sequence; exp(0)==1.0 exactly -> one f64 exp
  float c0 = cls[2 * i], c1 = cls[2 * i + 1];
  float m  = fmaxf(c0, c1);
  float a0 = c0 - m, a1 = c1 - m;          // one is exactly 0.0f
  float tn = fminf(a0, a1);
  float e  = (float)exp((double)tn);
  float e0 = (a0 == 0.0f) ? 1.0f : e;
  float e1 = (a1 == 0.0f) ? 1.0f : e;
  float s  = e1 / (e0 + e1);

  float4 a = ((const float4*)anchor)[i];
  float acx = (a.x + a.z) * 0.5f;
  float acy = (a.y + a.w) * 0.5f;
  float aw  = a.z - a.x;
  float ah  = a.w - a.y;
  float4 r = ((const float4*)reg)[i];
  float cx = r.x * aw + acx;
  float cy = r.y * ah + acy;
  float w  = (float)exp((double)r.z) * aw;
  float h  = (float)exp((double)r.w) * ah;
  float x1 = cx - w * 0.5f, y1 = cy - h * 0.5f;
  float x2 = cx + w * 0.5f, y2 = cy + h * 0.5f;
  x1 = fminf(fmaxf(x1, 0.0f), 1.0f);
  y1 = fminf(fmaxf(y1, 0.0f), 1.0f);
  x2 = fminf(fmaxf(x2, 0.0f), 1.0f);
  y2 = fminf(fmaxf(y2, 0.0f), 1.0f);
  float ws_ = x2 - x1, hs_ = y2 - y1;
  bool valid = (hs_ >= 0.001f) && (ws_ >= 0.001f);
  float msc = valid ? s : -__builtin_inff();
  uint32_t kk = score_key(msc);

  roi[i] = make_float4(x1, y1, x2, y2);
  key[i] = kk;
  // 8 histogram replicas (blockIdx&7): hottest line's serialized RMWs /8
  if (valid) atomicAdd(&hist16[((blockIdx.x & (NREP - 1)) << 16) + hslot(kk >> 16)], 1u);
}

// ---------------- 1b. reduce 8 replicas ----------------
__global__ void __launch_bounds__(256) k_hsum(const uint32_t* __restrict__ hist16,
                                              uint32_t* __restrict__ hists) {
  int i = blockIdx.x * 256 + threadIdx.x;  // 0..65535
  uint32_t s = 0;
#pragma unroll
  for (int r = 0; r < NREP; r++) s += hist16[(r << 16) + i];
  hists[i] = s;
}

// ---------------- 2. scan 65536-bin histogram (bit-reversed layout) ----------------
__global__ void __launch_bounds__(1024) k_scan16(const uint32_t* __restrict__ hists,
                                                 int* __restrict__ scal) {
  __shared__ unsigned short hh[65536];   // 128 KB
  __shared__ uint32_t part[1024];
  int t = threadIdx.x;
  const uint4* h4 = (const uint4*)hists;
#pragma unroll
  for (int k = 0; k < 16; k++) {
    uint4 v = h4[k * 1024 + t];
    uint32_t base = 4 * (k * 1024 + t);   // permuted-space index
    hh[__brev(base + 0) >> 16] = (unsigned short)v.x;  // brev is an involution
    hh[__brev(base + 1) >> 16] = (unsigned short)v.y;
    hh[__brev(base + 2) >> 16] = (unsigned short)v.z;
    hh[__brev(base + 3) >> 16] = (unsigned short)v.w;
  }
  __syncthreads();
  uint32_t sum = 0;
  for (int b = 0; b < 64; b++) sum += hh[t * 64 + b];
  part[t] = sum;
  __syncthreads();
  for (int off = 1; off < 1024; off <<= 1) {
    uint32_t v = (t >= off) ? part[t - off] : 0;
    __syncthreads();
    part[t] += v;
    __syncthreads();
  }
  if (t == 1023) scal[4] = (int)part[1023];   // total valid count
  uint32_t excl = part[t] - sum;
  if (excl < TOPK && excl + sum >= TOPK) {
    uint32_t cum = excl;
    for (int b = 0; b < 64; b++) {
      uint32_t h = hh[t * 64 + b];
      if (cum < TOPK && cum + h >= TOPK) { scal[0] = t * 64 + b; scal[1] = (int)cum; break; }
      cum += h;
    }
  }
}

// ---------------- 3. 8-bit refinement histogram ----------------
__global__ void k_hist8(const uint32_t* __restrict__ key, const int* __restrict__ scal,
                        uint32_t* __restrict__ hist8) {
  int i = blockIdx.x * blockDim.x + threadIdx.x;
  if (i >= NN) return;
  uint32_t P = (uint32_t)scal[0];
  uint32_t kk = key[i];
  if ((kk >> 16) == P) atomicAdd(&hist8[(kk >> 8) & 0xFFu], 1u);
}

__global__ void __launch_bounds__(256) k_scan8(const uint32_t* __restrict__ hist8,
                                               int* __restrict__ scal) {
  __shared__ uint32_t part[256];
  int t = threadIdx.x;
  uint32_t h = hist8[t];
  part[t] = h;
  __syncthreads();
  for (int off = 1; off < 256; off <<= 1) {
    uint32_t v = (t >= off) ? part[t - off] : 0;
    __syncthreads();
    part[t] += v;
    __syncthreads();
  }
  uint32_t excl = part[t] - h;
  uint32_t cb = (uint32_t)scal[1];
  if (cb + excl < TOPK && cb + excl + h >= TOPK)
    scal[2] = (scal[0] << 8) | t;
}

// ---------------- 4. compact candidates (prefix24 <= T24) ----------------
__global__ void k_compact(const uint32_t* __restrict__ key, int* __restrict__ scal,
                          unsigned long long* __restrict__ sortbuf) {
  __shared__ int lcnt, lbase;
  int t = threadIdx.x;
  int i = blockIdx.x * blockDim.x + t;
  if (t == 0) lcnt = 0;
  __syncthreads();
  bool sel = false;
  uint32_t kk = 0;
  int my = 0;
  if (i < NN) {
    uint32_t T24 = (uint32_t)scal[2];
    kk = key[i];
    if ((kk >> 8) <= T24) { sel = true; my = atomicAdd(&lcnt, 1); }
  }
  __syncthreads();
  if (t == 0 && lcnt > 0) lbase = atomicAdd(&scal[3], lcnt);
  __syncthreads();
  if (sel) {
    int pos = lbase + my;
    if (pos < SORTN) sortbuf[pos] = (((unsigned long long)kk) << 32) | (uint32_t)i;
  }
}

// ---------------- 5a. per-chunk bitonic sort (16 blocks x 512 elems, in place) --------
__global__ void __launch_bounds__(256) k_sortA(unsigned long long* __restrict__ sortbuf) {
  __shared__ unsigned long long sm[CSZ];
  int t = threadIdx.x;
  unsigned long long* chunk = sortbuf + (size_t)blockIdx.x * CSZ;
  sm[t] = chunk[t];
  sm[t + 256] = chunk[t + 256];
  __syncthreads();
  for (int k = 2; k <= CSZ; k <<= 1) {
    for (int j = k >> 1; j > 0; j >>= 1) {
      int i1 = ((t & ~(j - 1)) << 1) | (t & (j - 1));
      int i2 = i1 | j;
      bool up = ((i1 & k) == 0);
      unsigned long long a = sm[i1], b = sm[i2];
      if ((a > b) == up) { sm[i1] = b; sm[i2] = a; }
      __syncthreads();
    }
  }
  chunk[t] = sm[t];
  chunk[t + 256] = sm[t + 256];
}

// ---------------- 5b. stable multi-merge rank + scatter top-6000 ----------------
__global__ void __launch_bounds__(256) k_sortB(const unsigned long long* __restrict__ sortbuf,
                                               const float4* __restrict__ roi,
                                               float4* __restrict__ selbox) {
  int g = blockIdx.x * 256 + threadIdx.x;   // 0..8191
  int c = g >> 9, p = g & (CSZ - 1);
  unsigned long long val = sortbuf[g];
  int rank = p;
  for (int c2 = 0; c2 < NCHUNK; c2++) {
    if (c2 == c) continue;
    const unsigned long long* base = sortbuf + ((size_t)c2 << 9);
    bool le = (c2 < c);                     // earlier chunk: count <=, later: count <
    int pos = 0;
#pragma unroll
    for (int s = CSZ; s > 0; s >>= 1) {
      if (pos + s <= CSZ) {
        unsigned long long v = base[pos + s - 1];
        if (le ? (v <= val) : (v < val)) pos += s;
      }
    }
    rank += pos;
  }
  if (rank < (int)TOPK) {
    selbox[rank] = roi[(uint32_t)val];
  } else if (rank < KPAD) {
    selbox[rank] = make_float4(0.f, 0.f, 0.f, 0.f);
  }
}

// ---------------- 6. suppression: dense diagonal blocks + sparse inter-chunk entries ----
__global__ void __launch_bounds__(64) k_mask(const float4* __restrict__ selbox,
                                             unsigned long long* __restrict__ diag,
                                             uint32_t* __restrict__ ecnt,
                                             uint32_t* __restrict__ elist) {
  int bi = blockIdx.x, bj = blockIdx.y;
  if (bj < bi) return;
  int t = threadIdx.x;
  __shared__ float4 jb[64];
  __shared__ float  ja[64];
  int j0 = bj * 64;
  float4 cb = selbox[j0 + t];
  jb[t] = cb;
  ja[t] = (cb.z - cb.x) * (cb.w - cb.y);
  __syncthreads();
  int i = bi * 64 + t;
  unsigned long long word = 0;
  if (i < (int)TOPK) {
    float4 bi4 = selbox[i];
    float ai = (bi4.z - bi4.x) * (bi4.w - bi4.y);
    for (int jj = 0; jj < 64; jj++) {
      int j = j0 + jj;
      float4 bb = jb[jj];
      float ltx = fmaxf(bi4.x, bb.x), lty = fmaxf(bi4.y, bb.y);
      float rbx = fminf(bi4.z, bb.z), rby = fminf(bi4.w, bb.w);
      float wx = fmaxf(rbx - ltx, 0.0f), wy = fmaxf(rby - lty, 0.0f);
      float inter = wx * wy;
      float iou = inter / (ai + ja[jj] - inter + 1e-9f);
      if (iou > 0.7f && j > i && j < (int)TOPK) word |= (1ull << jj);
    }
  }
  if (bi == bj) {
    diag[i] = word;
    return;
  }
  // sparse append: wave-prefix over per-thread popcounts, one atomic per block
  uint32_t cnt = (uint32_t)__popcll(word);
  uint32_t pre = cnt;
#pragma unroll
  for (int off = 1; off < 64; off <<= 1) {
    uint32_t v = __shfl_up(pre, off);
    if (t >= off) pre += v;
  }
  uint32_t total = __shfl(pre, 63);
  if (total == 0) return;                 // wave-uniform
  uint32_t excl = pre - cnt;
  uint32_t base;
  if (t == 0) base = atomicAdd(&ecnt[bi], total);
  base = __shfl(base, 0);
  unsigned long long rem = word;
  uint32_t k = 0;
  while (rem) {
    int jj = (int)__builtin_ctzll(rem);
    rem &= rem - 1;
    uint32_t pos = base + excl + k;
    k++;
    if (pos < ECAP) elist[(size_t)bi * ECAP + pos] = ((uint32_t)t << 16) | (uint32_t)(j0 + jj);
  }
}

// ---------------- 7. greedy keep: single-wave, register-resident ----------------
// Stage diag (48KB) + sparse entries into LDS once (3 barriers), then wave 0
// runs all 94 chunks with ZERO barriers and ZERO global loads. Keep bitmap in
// lane registers: lane l owns chunks l (kA) and l+64 (kB). Chunk word reads via
// uniform readlane; diag rows ds_read-prefetched one chunk ahead.
__global__ void __launch_bounds__(256) k_seq(const unsigned long long* __restrict__ diag,
                                             const uint32_t* __restrict__ ecnt,
                                             const uint32_t* __restrict__ elist,
                                             const int* __restrict__ scal,
                                             const float4* __restrict__ selbox,
                                             float* __restrict__ out) {
  __shared__ unsigned long long dlds[KPAD];   // 48128 B
  __shared__ uint32_t elds[ELDS];             // 12288 B
  __shared__ uint32_t scnt_l[KW];
  __shared__ uint32_t eoffs[KW + 1];
  __shared__ uint32_t keep32[2 * KW];
  __shared__ uint32_t wrank[KW];
  const int t = threadIdx.x;

  for (int i = t; i < KPAD / 2; i += 256)
    ((ulonglong2*)dlds)[i] = ((const ulonglong2*)diag)[i];
  if (t < KW) scnt_l[t] = min(ecnt[t], (uint32_t)ECAP);
  __syncthreads();
  if (t == 0) {
    uint32_t run = 0;
    for (int c = 0; c < KW; c++) { eoffs[c] = run; run += scnt_l[c]; }
    eoffs[KW] = run;
  }
  __syncthreads();
  for (int c = 0; c < KW; c++) {
    uint32_t cnt = scnt_l[c], base = eoffs[c];
    for (uint32_t k = t; k < cnt; k += 256)
      if (base + k < ELDS) elds[base + k] = elist[(size_t)c * ECAP + k];
  }
  __syncthreads();

  if (t < 64) {
    const int lane = t;
    int V = scal[4];
    if (V > (int)TOPK) V = (int)TOPK;
    unsigned long long kA, kB;
    {
      int base = lane * 64;
      kA = (V <= base) ? 0ull : ((V - base >= 64) ? ~0ull : ((1ull << (V - base)) - 1));
      int base2 = (lane + 64) * 64;
      kB = (lane + 64 < KW)
               ? ((V <= base2) ? 0ull : ((V - base2 >= 64) ? ~0ull : ((1ull << (V - base2)) - 1)))
               : 0ull;
    }
    unsigned long long mb = dlds[lane];       // chunk 0 row
    for (int c = 0; c < KW; c++) {
      unsigned long long mbn = (c + 1 < KW) ? dlds[(c + 1) * 64 + lane] : 0ull;  // prefetch
      uint32_t wlo, whi;
      if (c < 64) {
        wlo = __builtin_amdgcn_readlane((uint32_t)kA, c);
        whi = __builtin_amdgcn_readlane((uint32_t)(kA >> 32), c);
      } else {
        wlo = __builtin_amdgcn_readlane((uint32_t)kB, c - 64);
        whi = __builtin_amdgcn_readlane((uint32_t)(kB >> 32), c - 64);
      }
      unsigned long long w = ((unsigned long long)whi << 32) | wlo;
      unsigned long long sup = __ballot(mb != 0);
      unsigned long long rem = w & sup;
      while (rem) {
        int b = (int)__builtin_ctzll(rem);
        uint32_t mlo = __builtin_amdgcn_readlane((uint32_t)mb, b);
        uint32_t mhi = __builtin_amdgcn_readlane((uint32_t)(mb >> 32), b);
        w &= ~(((unsigned long long)mhi << 32) | mlo);
        rem = (b >= 63) ? 0ull : (w & sup & (~0ull << (b + 1)));
      }
      if (c < 64) { if (lane == c) kA = w; }
      else        { if (lane == c - 64) kB = w; }
      // phase 2: uniform sequential application of chunk c's sparse entries
      uint32_t cnt = scnt_l[c], base = eoffs[c];
      for (uint32_t k = 0; k < cnt; k++) {
        uint32_t e = (base + k < ELDS) ? elds[base + k] : elist[(size_t)c * ECAP + k];
        int il = (int)(e >> 16), j = (int)(e & 0xFFFFu);
        if ((w >> il) & 1ull) {
          int jc = j >> 6;
          unsigned long long bit = 1ull << (j & 63);
          if (jc < 64) { if (lane == jc) kA &= ~bit; }
          else         { if (lane == jc - 64) kB &= ~bit; }
        }
      }
      mb = mbn;
    }
    keep32[2 * lane]     = (uint32_t)kA;
    keep32[2 * lane + 1] = (uint32_t)(kA >> 32);
    if (lane + 64 < KW) {
      keep32[2 * (lane + 64)]     = (uint32_t)kB;
      keep32[2 * (lane + 64) + 1] = (uint32_t)(kB >> 32);
    }
  }
  __syncthreads();

  // ranks of kept rows
  if (t == 0) {
    uint32_t cum = 0;
    for (int w = 0; w < KW; w++) {
      wrank[w] = cum;
      cum += (uint32_t)(__popc(keep32[2 * w]) + __popc(keep32[2 * w + 1]));
    }
  }
  __syncthreads();
  for (int o = t; o < OUTK * 4; o += 256) out[o] = 0.0f;
  __syncthreads();
  for (int r = t; r < (int)TOPK; r += 256) {
    unsigned long long w =
        ((unsigned long long)keep32[2 * (r >> 6) + 1] << 32) | keep32[2 * (r >> 6)];
    int b = r & 63;
    if ((w >> b) & 1ull) {
      uint32_t rank = wrank[r >> 6] + (uint32_t)__popcll(w & ((1ull << b) - 1ull));
      if (rank < OUTK) {
        float4 bx = selbox[r];
        out[rank * 4 + 0] = bx.x;
        out[rank * 4 + 1] = bx.y;
        out[rank * 4 + 2] = bx.z;
        out[rank * 4 + 3] = bx.w;
      }
    }
  }
}

// ---------------- launch ----------------
extern "C" void kernel_launch(void* const* d_in, const int* in_sizes, int n_in,
                              void* d_out, int out_size, void* d_ws, size_t ws_size,
                              hipStream_t stream) {
  const float* cls    = (const float*)d_in[0];
  const float* reg    = (const float*)d_in[1];
  const float* anchor = (const float*)d_in[2];
  float* out = (float*)d_out;
  char* ws = (char*)d_ws;

  float4*   roi     = (float4*)(ws + OFF_ROI);
  uint32_t* key     = (uint32_t*)(ws + OFF_KEY);
  uint32_t* hist16  = (uint32_t*)(ws + OFF_HIST16);
  uint32_t* hists   = (uint32_t*)(ws + OFF_HISTS);
  uint32_t* hist8   = (uint32_t*)(ws + OFF_HIST8);
  int*      scal    = (int*)(ws + OFF_SCAL);
  uint32_t* ecnt    = (uint32_t*)(ws + OFF_ECNT);
  unsigned long long* sortbuf = (unsigned long long*)(ws + OFF_SORT);
  float4*   selbox  = (float4*)(ws + OFF_SELBOX);
  unsigned long long* diag = (unsigned long long*)(ws + OFF_DIAG);
  uint32_t* elist   = (uint32_t*)(ws + OFF_ELIST);

  hipMemsetAsync(ws + OFF_HIST16, 0, ZERO_BYTES, stream);
  hipMemsetAsync(ws + OFF_SORT, 0xFF, (size_t)SORTN * 8, stream);

  int blocks = (NN + 255) / 256;
  k_decode<<<blocks, 256, 0, stream>>>(cls, reg, anchor, roi, key, hist16);
  k_hsum<<<65536 / 256, 256, 0, stream>>>(hist16, hists);
  k_scan16<<<1, 1024, 0, stream>>>(hists, scal);
  k_hist8<<<blocks, 256, 0, stream>>>(key, scal, hist8);
  k_scan8<<<1, 256, 0, stream>>>(hist8, scal);
  k_compact<<<blocks, 256, 0, stream>>>(key, scal, sortbuf);
  k_sortA<<<NCHUNK, 256, 0, stream>>>(sortbuf);
  k_sortB<<<SORTN / 256, 256, 0, stream>>>(sortbuf, roi, selbox);
  k_mask<<<dim3(KW, KW), 64, 0, stream>>>(selbox, diag, ecnt, elist);
  k_seq<<<1, 256, 0, stream>>>(diag, ecnt, elist, scal, selbox, out);
}

// Round 9
// 209.097 us; speedup vs baseline: 1.5049x; 1.5049x over previous
//
#include <hip/hip_runtime.h>
#include <stdint.h>

#pragma clang fp contract(off)

#define NN    300000
#define TOPK  6000u
#define KW    94
#define KPAD  6016
#define SORTN 8192
#define NCHUNK 16
#define CSZ   512
#define OUTK  300
#define ECAP  8192
#define ELDS  6144
#define NREP  8

// ---------------- workspace layout (bytes) ----------------
static constexpr size_t OFF_ROI    = 0;                                   // NN*16
static constexpr size_t OFF_KEY    = OFF_ROI + (size_t)NN * 16;           // NN*4
static constexpr size_t OFF_HIST16 = ((OFF_KEY + (size_t)NN * 4 + 255) & ~(size_t)255); // NREP*65536*4
static constexpr size_t OFF_HIST8  = OFF_HIST16 + (size_t)NREP * 65536 * 4; // 256*4
static constexpr size_t OFF_SCAL   = OFF_HIST8 + 256 * 4;                 // 256 B scalars
static constexpr size_t OFF_ECNT   = OFF_SCAL + 256;                      // 94*4, pad 512
static constexpr size_t ZERO_BYTES = (OFF_ECNT + 512) - OFF_HIST16;
static constexpr size_t OFF_HISTS  = OFF_ECNT + 512;                      // 65536*4 (summed, no zeroing)
static constexpr size_t OFF_SORT   = OFF_HISTS + 65536 * 4;               // SORTN*8
static constexpr size_t OFF_SELBOX = OFF_SORT + (size_t)SORTN * 8;        // KPAD*16
static constexpr size_t OFF_DIAG   = ((OFF_SELBOX + (size_t)KPAD * 16 + 255) & ~(size_t)255); // KPAD*8
static constexpr size_t OFF_ELIST  = OFF_DIAG + (size_t)KPAD * 8;         // KW*ECAP*4 ~= 3.0 MB

// scal[] layout: [0]=P16 bin, [1]=count_below16, [2]=T24 prefix, [3]=compact counter,
//                [4]=total valid count

__device__ __forceinline__ uint32_t score_key(float s) {
  uint32_t u = __float_as_uint(s);
  u = (u >> 31) ? ~u : (u | 0x80000000u);  // monotonic: ascending uint == ascending float
  return ~u;                               // invert: ascending uint == DESCENDING float
}

// bit-reversed histogram slot: consecutive bins -> distinct cache lines.
__device__ __forceinline__ uint32_t hslot(uint32_t b) { return __brev(b) >> 16; }

// ---------------- 1. decode + key + replicated 16-bit histogram ----------------
__global__ void k_decode(const float* __restrict__ cls, const float* __restrict__ reg,
                         const float* __restrict__ anchor, float4* __restrict__ roi,
                         uint32_t* __restrict__ key, uint32_t* __restrict__ hist16) {
  int i = blockIdx.x * blockDim.x + threadIdx.x;
  if (i >= NN) return;
  // softmax(cls)[1], bit-identical op sequence; exp(0)==1.0 exactly -> one f64 exp
  float c0 = cls[2 * i], c1 = cls[2 * i + 1];
  float m  = fmaxf(c0, c1);
  float a0 = c0 - m, a1 = c1 - m;          // one is exactly 0.0f
  float tn = fminf(a0, a1);
  float e  = (float)exp((double)tn);
  float e0 = (a0 == 0.0f) ? 1.0f : e;
  float e1 = (a1 == 0.0f) ? 1.0f : e;
  float s  = e1 / (e0 + e1);

  float4 a = ((const float4*)anchor)[i];
  float acx = (a.x + a.z) * 0.5f;
  float acy = (a.y + a.w) * 0.5f;
  float aw  = a.z - a.x;
  float ah  = a.w - a.y;
  float4 r = ((const float4*)reg)[i];
  float cx = r.x * aw + acx;
  float cy = r.y * ah + acy;
  float w  = (float)exp((double)r.z) * aw;
  float h  = (float)exp((double)r.w) * ah;
  float x1 = cx - w * 0.5f, y1 = cy - h * 0.5f;
  float x2 = cx + w * 0.5f, y2 = cy + h * 0.5f;
  x1 = fminf(fmaxf(x1, 0.0f), 1.0f);
  y1 = fminf(fmaxf(y1, 0.0f), 1.0f);
  x2 = fminf(fmaxf(x2, 0.0f), 1.0f);
  y2 = fminf(fmaxf(y2, 0.0f), 1.0f);
  float ws_ = x2 - x1, hs_ = y2 - y1;
  bool valid = (hs_ >= 0.001f) && (ws_ >= 0.001f);
  float msc = valid ? s : -__builtin_inff();
  uint32_t kk = score_key(msc);

  roi[i] = make_float4(x1, y1, x2, y2);
  key[i] = kk;
  // 8 histogram replicas (blockIdx&7): hottest line's serialized RMWs /8
  if (valid) atomicAdd(&hist16[((blockIdx.x & (NREP - 1)) << 16) + hslot(kk >> 16)], 1u);
}

// ---------------- 1b. reduce 8 replicas ----------------
__global__ void __launch_bounds__(256) k_hsum(const uint32_t* __restrict__ hist16,
                                              uint32_t* __restrict__ hists) {
  int i = blockIdx.x * 256 + threadIdx.x;  // 0..65535
  uint32_t s = 0;
#pragma unroll
  for (int r = 0; r < NREP; r++) s += hist16[(r << 16) + i];
  hists[i] = s;
}

// ---------------- 2. scan 65536-bin histogram (bit-reversed layout) ----------------
__global__ void __launch_bounds__(1024) k_scan16(const uint32_t* __restrict__ hists,
                                                 int* __restrict__ scal) {
  __shared__ unsigned short hh[65536];   // 128 KB
  __shared__ uint32_t part[1024];
  int t = threadIdx.x;
  const uint4* h4 = (const uint4*)hists;
#pragma unroll
  for (int k = 0; k < 16; k++) {
    uint4 v = h4[k * 1024 + t];
    uint32_t base = 4 * (k * 1024 + t);   // permuted-space index
    hh[__brev(base + 0) >> 16] = (unsigned short)v.x;  // brev is an involution
    hh[__brev(base + 1) >> 16] = (unsigned short)v.y;
    hh[__brev(base + 2) >> 16] = (unsigned short)v.z;
    hh[__brev(base + 3) >> 16] = (unsigned short)v.w;
  }
  __syncthreads();
  uint32_t sum = 0;
  for (int b = 0; b < 64; b++) sum += hh[t * 64 + b];
  part[t] = sum;
  __syncthreads();
  for (int off = 1; off < 1024; off <<= 1) {
    uint32_t v = (t >= off) ? part[t - off] : 0;
    __syncthreads();
    part[t] += v;
    __syncthreads();
  }
  if (t == 1023) scal[4] = (int)part[1023];   // total valid count
  uint32_t excl = part[t] - sum;
  if (excl < TOPK && excl + sum >= TOPK) {
    uint32_t cum = excl;
    for (int b = 0; b < 64; b++) {
      uint32_t h = hh[t * 64 + b];
      if (cum < TOPK && cum + h >= TOPK) { scal[0] = t * 64 + b; scal[1] = (int)cum; break; }
      cum += h;
    }
  }
}

// ---------------- 3. 8-bit refinement histogram ----------------
__global__ void k_hist8(const uint32_t* __restrict__ key, const int* __restrict__ scal,
                        uint32_t* __restrict__ hist8) {
  int i = blockIdx.x * blockDim.x + threadIdx.x;
  if (i >= NN) return;
  uint32_t P = (uint32_t)scal[0];
  uint32_t kk = key[i];
  if ((kk >> 16) == P) atomicAdd(&hist8[(kk >> 8) & 0xFFu], 1u);
}

__global__ void __launch_bounds__(256) k_scan8(const uint32_t* __restrict__ hist8,
                                               int* __restrict__ scal) {
  __shared__ uint32_t part[256];
  int t = threadIdx.x;
  uint32_t h = hist8[t];
  part[t] = h;
  __syncthreads();
  for (int off = 1; off < 256; off <<= 1) {
    uint32_t v = (t >= off) ? part[t - off] : 0;
    __syncthreads();
    part[t] += v;
    __syncthreads();
  }
  uint32_t excl = part[t] - h;
  uint32_t cb = (uint32_t)scal[1];
  if (cb + excl < TOPK && cb + excl + h >= TOPK)
    scal[2] = (scal[0] << 8) | t;
}

// ---------------- 4. compact candidates (prefix24 <= T24) ----------------
__global__ void k_compact(const uint32_t* __restrict__ key, int* __restrict__ scal,
                          unsigned long long* __restrict__ sortbuf) {
  __shared__ int lcnt, lbase;
  int t = threadIdx.x;
  int i = blockIdx.x * blockDim.x + t;
  if (t == 0) lcnt = 0;
  __syncthreads();
  bool sel = false;
  uint32_t kk = 0;
  int my = 0;
  if (i < NN) {
    uint32_t T24 = (uint32_t)scal[2];
    kk = key[i];
    if ((kk >> 8) <= T24) { sel = true; my = atomicAdd(&lcnt, 1); }
  }
  __syncthreads();
  if (t == 0 && lcnt > 0) lbase = atomicAdd(&scal[3], lcnt);
  __syncthreads();
  if (sel) {
    int pos = lbase + my;
    if (pos < SORTN) sortbuf[pos] = (((unsigned long long)kk) << 32) | (uint32_t)i;
  }
}

// ---------------- 5a. per-chunk bitonic sort (16 blocks x 512 elems, in place) --------
__global__ void __launch_bounds__(256) k_sortA(unsigned long long* __restrict__ sortbuf) {
  __shared__ unsigned long long sm[CSZ];
  int t = threadIdx.x;
  unsigned long long* chunk = sortbuf + (size_t)blockIdx.x * CSZ;
  sm[t] = chunk[t];
  sm[t + 256] = chunk[t + 256];
  __syncthreads();
  for (int k = 2; k <= CSZ; k <<= 1) {
    for (int j = k >> 1; j > 0; j >>= 1) {
      int i1 = ((t & ~(j - 1)) << 1) | (t & (j - 1));
      int i2 = i1 | j;
      bool up = ((i1 & k) == 0);
      unsigned long long a = sm[i1], b = sm[i2];
      if ((a > b) == up) { sm[i1] = b; sm[i2] = a; }
      __syncthreads();
    }
  }
  chunk[t] = sm[t];
  chunk[t + 256] = sm[t + 256];
}

// ---------------- 5b. stable multi-merge rank + scatter top-6000 ----------------
__global__ void __launch_bounds__(256) k_sortB(const unsigned long long* __restrict__ sortbuf,
                                               const float4* __restrict__ roi,
                                               float4* __restrict__ selbox) {
  int g = blockIdx.x * 256 + threadIdx.x;   // 0..8191
  int c = g >> 9, p = g & (CSZ - 1);
  unsigned long long val = sortbuf[g];
  int rank = p;
  for (int c2 = 0; c2 < NCHUNK; c2++) {
    if (c2 == c) continue;
    const unsigned long long* base = sortbuf + ((size_t)c2 << 9);
    bool le = (c2 < c);                     // earlier chunk: count <=, later: count <
    int pos = 0;
#pragma unroll
    for (int s = CSZ; s > 0; s >>= 1) {
      if (pos + s <= CSZ) {
        unsigned long long v = base[pos + s - 1];
        if (le ? (v <= val) : (v < val)) pos += s;
      }
    }
    rank += pos;
  }
  if (rank < (int)TOPK) {
    selbox[rank] = roi[(uint32_t)val];
  } else if (rank < KPAD) {
    selbox[rank] = make_float4(0.f, 0.f, 0.f, 0.f);
  }
}

// ---------------- 6. suppression: dense diagonal blocks + sparse inter-chunk entries ----
__global__ void __launch_bounds__(64) k_mask(const float4* __restrict__ selbox,
                                             unsigned long long* __restrict__ diag,
                                             uint32_t* __restrict__ ecnt,
                                             uint32_t* __restrict__ elist) {
  int bi = blockIdx.x, bj = blockIdx.y;
  if (bj < bi) return;
  int t = threadIdx.x;
  __shared__ float4 jb[64];
  __shared__ float  ja[64];
  int j0 = bj * 64;
  float4 cb = selbox[j0 + t];
  jb[t] = cb;
  ja[t] = (cb.z - cb.x) * (cb.w - cb.y);
  __syncthreads();
  int i = bi * 64 + t;
  unsigned long long word = 0;
  if (i < (int)TOPK) {
    float4 bi4 = selbox[i];
    float ai = (bi4.z - bi4.x) * (bi4.w - bi4.y);
    for (int jj = 0; jj < 64; jj++) {
      int j = j0 + jj;
      float4 bb = jb[jj];
      float ltx = fmaxf(bi4.x, bb.x), lty = fmaxf(bi4.y, bb.y);
      float rbx = fminf(bi4.z, bb.z), rby = fminf(bi4.w, bb.w);
      float wx = fmaxf(rbx - ltx, 0.0f), wy = fmaxf(rby - lty, 0.0f);
      float inter = wx * wy;
      float iou = inter / (ai + ja[jj] - inter + 1e-9f);
      if (iou > 0.7f && j > i && j < (int)TOPK) word |= (1ull << jj);
    }
  }
  if (bi == bj) {
    diag[i] = word;
    return;
  }
  // sparse append: wave-prefix over per-thread popcounts, one atomic per block
  uint32_t cnt = (uint32_t)__popcll(word);
  uint32_t pre = cnt;
#pragma unroll
  for (int off = 1; off < 64; off <<= 1) {
    uint32_t v = __shfl_up(pre, off);
    if (t >= off) pre += v;
  }
  uint32_t total = __shfl(pre, 63);
  if (total == 0) return;                 // wave-uniform
  uint32_t excl = pre - cnt;
  uint32_t base;
  if (t == 0) base = atomicAdd(&ecnt[bi], total);
  base = __shfl(base, 0);
  unsigned long long rem = word;
  uint32_t k = 0;
  while (rem) {
    int jj = (int)__builtin_ctzll(rem);
    rem &= rem - 1;
    uint32_t pos = base + excl + k;
    k++;
    if (pos < ECAP) elist[(size_t)bi * ECAP + pos] = ((uint32_t)t << 16) | (uint32_t)(j0 + jj);
  }
}

// ---------------- 7. greedy keep: single-wave, barrier-free, LANE-PARALLEL phase 2 ----
// Keep bitmap in LDS keep32[]; per chunk: one ds_read of keep word (only
// non-prefetchable load), ballot walk from register diag row (prefetched 1
// ahead), lane 0 write-back, then 64 lanes apply sparse entries in parallel
// via LDS atomicAnd (entries + base/cnt also prefetched 1 ahead - static
// data, and phase-2 targets are strictly later chunks so never stale).
// Single wave => LDS FIFO ordering makes chunk-c read see earlier atomics.
__global__ void __launch_bounds__(256) k_seq(const unsigned long long* __restrict__ diag,
                                             const uint32_t* __restrict__ ecnt,
                                             const uint32_t* __restrict__ elist,
                                             const int* __restrict__ scal,
                                             const float4* __restrict__ selbox,
                                             float* __restrict__ out) {
  __shared__ unsigned long long dlds[KPAD];   // 48128 B
  __shared__ uint32_t elds[ELDS];             // 24576 B
  __shared__ uint32_t scnt_l[KW];
  __shared__ uint32_t eoffs[KW + 1];
  __shared__ uint32_t keep32[2 * KW];
  __shared__ uint32_t wrank[KW];
  const int t = threadIdx.x;

  for (int i = t; i < KPAD / 2; i += 256)
    ((ulonglong2*)dlds)[i] = ((const ulonglong2*)diag)[i];
  if (t < KW) scnt_l[t] = min(ecnt[t], (uint32_t)ECAP);
  __syncthreads();
  if (t == 0) {
    uint32_t run = 0;
    for (int c = 0; c < KW; c++) { eoffs[c] = run; run += scnt_l[c]; }
    eoffs[KW] = run;
  }
  __syncthreads();
  for (int c = 0; c < KW; c++) {
    uint32_t cnt = scnt_l[c], base = eoffs[c];
    for (uint32_t k = t; k < cnt; k += 256)
      if (base + k < ELDS) elds[base + k] = elist[(size_t)c * ECAP + k];
  }
  // init keep words from valid-prefix V (valid boxes are a prefix of sort order)
  {
    int V = scal[4];
    if (V > (int)TOPK) V = (int)TOPK;
    if (t < 2 * KW) {
      int d = V - t * 32;
      keep32[t] = (d <= 0) ? 0u : ((d >= 32) ? 0xFFFFFFFFu : ((1u << d) - 1u));
    }
  }
  __syncthreads();

  if (t < 64) {
    const int lane = t;
    // prefetched state for chunk 0
    unsigned long long mb = dlds[lane];
    uint32_t base = eoffs[0], cnt = scnt_l[0];
    uint32_t ew = 0;
    if ((uint32_t)lane < cnt)
      ew = (base + lane < ELDS) ? elds[base + lane] : elist[lane];
    for (int c = 0; c < KW; c++) {
      // prefetch chunk c+1 state (static after staging; targets of phase 2
      // are strictly > c, so none of this is ever stale)
      unsigned long long mbn = 0;
      uint32_t basen = 0, cntn = 0, ewn = 0;
      if (c + 1 < KW) {
        mbn = dlds[(c + 1) * 64 + lane];
        basen = eoffs[c + 1];
        cntn = scnt_l[c + 1];
        if ((uint32_t)lane < cntn)
          ewn = (basen + lane < ELDS) ? elds[basen + lane]
                                      : elist[(size_t)(c + 1) * ECAP + lane];
      }
      // read current keep word (the one serial-latency load per chunk)
      unsigned long long w =
          ((unsigned long long)keep32[2 * c + 1] << 32) | keep32[2 * c];
      // phase 1: ballot walk over kept suppressor bits
      unsigned long long sup = __ballot(mb != 0);
      unsigned long long rem = w & sup;
      while (rem) {
        int b = (int)__builtin_ctzll(rem);
        uint32_t mlo = __builtin_amdgcn_readlane((uint32_t)mb, b);
        uint32_t mhi = __builtin_amdgcn_readlane((uint32_t)(mb >> 32), b);
        w &= ~(((unsigned long long)mhi << 32) | mlo);
        rem = (b >= 63) ? 0ull : (w & sup & (~0ull << (b + 1)));
      }
      if (lane == 0) {
        keep32[2 * c] = (uint32_t)w;
        keep32[2 * c + 1] = (uint32_t)(w >> 32);
      }
      // phase 2: lane-parallel sparse entry application (targets j in chunks > c)
      for (uint32_t k0 = 0; k0 < cnt; k0 += 64) {
        uint32_t k = k0 + (uint32_t)lane;
        if (k < cnt) {
          uint32_t e;
          if (k0 == 0) e = ew;
          else e = (base + k < ELDS) ? elds[base + k] : elist[(size_t)c * ECAP + k];
          int il = (int)(e >> 16), j = (int)(e & 0xFFFFu);
          if ((w >> il) & 1ull)
            atomicAnd(&keep32[j >> 5], ~(1u << (j & 31)));
        }
      }
      mb = mbn; base = basen; cnt = cntn; ew = ewn;
    }
  }
  __syncthreads();

  // ranks of kept rows
  if (t == 0) {
    uint32_t cum = 0;
    for (int w = 0; w < KW; w++) {
      wrank[w] = cum;
      cum += (uint32_t)(__popc(keep32[2 * w]) + __popc(keep32[2 * w + 1]));
    }
  }
  __syncthreads();
  for (int o = t; o < OUTK * 4; o += 256) out[o] = 0.0f;
  __syncthreads();
  for (int r = t; r < (int)TOPK; r += 256) {
    unsigned long long w =
        ((unsigned long long)keep32[2 * (r >> 6) + 1] << 32) | keep32[2 * (r >> 6)];
    int b = r & 63;
    if ((w >> b) & 1ull) {
      uint32_t rank = wrank[r >> 6] + (uint32_t)__popcll(w & ((1ull << b) - 1ull));
      if (rank < OUTK) {
        float4 bx = selbox[r];
        out[rank * 4 + 0] = bx.x;
        out[rank * 4 + 1] = bx.y;
        out[rank * 4 + 2] = bx.z;
        out[rank * 4 + 3] = bx.w;
      }
    }
  }
}

// ---------------- launch ----------------
extern "C" void kernel_launch(void* const* d_in, const int* in_sizes, int n_in,
                              void* d_out, int out_size, void* d_ws, size_t ws_size,
                              hipStream_t stream) {
  const float* cls    = (const float*)d_in[0];
  const float* reg    = (const float*)d_in[1];
  const float* anchor = (const float*)d_in[2];
  float* out = (float*)d_out;
  char* ws = (char*)d_ws;

  float4*   roi     = (float4*)(ws + OFF_ROI);
  uint32_t* key     = (uint32_t*)(ws + OFF_KEY);
  uint32_t* hist16  = (uint32_t*)(ws + OFF_HIST16);
  uint32_t* hists   = (uint32_t*)(ws + OFF_HISTS);
  uint32_t* hist8   = (uint32_t*)(ws + OFF_HIST8);
  int*      scal    = (int*)(ws + OFF_SCAL);
  uint32_t* ecnt    = (uint32_t*)(ws + OFF_ECNT);
  unsigned long long* sortbuf = (unsigned long long*)(ws + OFF_SORT);
  float4*   selbox  = (float4*)(ws + OFF_SELBOX);
  unsigned long long* diag = (unsigned long long*)(ws + OFF_DIAG);
  uint32_t* elist   = (uint32_t*)(ws + OFF_ELIST);

  hipMemsetAsync(ws + OFF_HIST16, 0, ZERO_BYTES, stream);
  hipMemsetAsync(ws + OFF_SORT, 0xFF, (size_t)SORTN * 8, stream);

  int blocks = (NN + 255) / 256;
  k_decode<<<blocks, 256, 0, stream>>>(cls, reg, anchor, roi, key, hist16);
  k_hsum<<<65536 / 256, 256, 0, stream>>>(hist16, hists);
  k_scan16<<<1, 1024, 0, stream>>>(hists, scal);
  k_hist8<<<blocks, 256, 0, stream>>>(key, scal, hist8);
  k_scan8<<<1, 256, 0, stream>>>(hist8, scal);
  k_compact<<<blocks, 256, 0, stream>>>(key, scal, sortbuf);
  k_sortA<<<NCHUNK, 256, 0, stream>>>(sortbuf);
  k_sortB<<<SORTN / 256, 256, 0, stream>>>(sortbuf, roi, selbox);
  k_mask<<<dim3(KW, KW), 64, 0, stream>>>(selbox, diag, ecnt, elist);
  k_seq<<<1, 256, 0, stream>>>(diag, ecnt, elist, scal, selbox, out);
}